// Round 4
// baseline (369.829 us; speedup 1.0000x reference)
//
#include <hip/hip_runtime.h>
#include <stdint.h>

// Batched tiny MLP [B,13]->16->(30x 16->16 relu)->1, fp32 in/out, bf16 MFMA.
// Transposed formulation: mfma_f32_16x16x16_bf16 D layout == B layout, so each
// layer's relu'd output is the next layer's B fragment in-register.
// R4: issue-port diet. No LDS for x at all -- each lane loads its fragment
// bytes straight from global (dword-aligned 16B, g==3 shifted to offset 9 and
// masked, since A is zero for k>=13). Single base pointer + immediate offsets.
// Biases in LDS (2 KB) as the MFMA C operand. A-fragments in registers.

typedef __attribute__((ext_vector_type(4))) short short4v;
typedef __attribute__((ext_vector_type(4))) float float4v;

#define S_IN 13
#define H 16
#define NL 32          // mfma layers: 0 = input, 1..30 = hidden, 31 = output
#define TPB 256
#define WPB 4          // waves per block
#define T 4            // 16-sample tiles per wave per iteration
#define NBLOCKS 1024
#define STRIDE (NBLOCKS * WPB * T)   // tiles per grid sweep = 16384

__device__ __forceinline__ unsigned pk_bf16(float a, float b) {
#if __has_builtin(__builtin_amdgcn_cvt_pk_bf16_f32)
    typedef __attribute__((ext_vector_type(2))) __bf16 bf16x2;
    bf16x2 v = __builtin_amdgcn_cvt_pk_bf16_f32(a, b);
    return __builtin_bit_cast(unsigned, v);
#else
    // RNE pack: 2x(bfe+add3) + 1 v_perm  (high halves of a,b -> one dword)
    unsigned ra = __float_as_uint(a), rb = __float_as_uint(b);
    ra += 0x7fffu + ((ra >> 16) & 1u);
    rb += 0x7fffu + ((rb >> 16) & 1u);
    return __builtin_amdgcn_perm(rb, ra, 0x07060302u);
#endif
}

__device__ __forceinline__ short4v pack4(float v0, float v1, float v2, float v3) {
    int2 p;
    p.x = (int)pk_bf16(v0, v1);
    p.y = (int)pk_bf16(v2, v3);
    return __builtin_bit_cast(short4v, p);
}

__device__ __forceinline__ float4v ld16u(const float* p) {
    float4v v;
    __builtin_memcpy(&v, p, 16);   // dword-aligned global load
    return v;
}

__global__ __launch_bounds__(TPB, 4)
void mlp_kernel(const float* __restrict__ x,
                const float* __restrict__ W_in, const float* __restrict__ b_in,
                const float* __restrict__ W_h,  const float* __restrict__ b_h,
                const float* __restrict__ W_out,const float* __restrict__ b_out,
                float* __restrict__ out, int tiles)
{
    __shared__ float4v biasL[NL * 4];   // [L][g] = bias rows 4g..4g+3 (C frag)
    const int tid = threadIdx.x;
    if (tid < NL * 4) {
        const int L = tid >> 2, gg = tid & 3;
        float4v bv;
#pragma unroll
        for (int j = 0; j < 4; ++j) {
            const int mm = 4 * gg + j;
            float v;
            if (L == 0)       v = b_in[mm];
            else if (L <= 30) v = b_h[(L - 1) * H + mm];
            else              v = (mm == 0) ? b_out[0] : 0.f;
            bv[j] = v;
        }
        biasL[tid] = bv;
    }
    __syncthreads();

    const int lane = tid & 63;
    const int wv   = tid >> 6;
    const int g    = lane >> 4;
    const int col  = lane & 15;        // sample within tile == A row m
    const int k0   = 4 * g;
    const bool g3  = (g == 3);
    const int offk = g3 ? 9 : k0;      // g3 loads k=9..12, keeps only k=12

    // ---- A fragments for all 32 layers in registers (once per wave) ----
    short4v aF[NL];
    {
        float4v w = ld16u(W_in + col * S_IN + offk);
        float v0 = g3 ? w[3] : w[0];
        float v1 = g3 ? 0.f : w[1];
        float v2 = g3 ? 0.f : w[2];
        float v3 = g3 ? 0.f : w[3];
        aF[0] = pack4(v0, v1, v2, v3);
    }
#pragma unroll
    for (int L = 1; L <= 30; ++L) {
        float4v w = ld16u(W_h + (size_t)(L - 1) * 256 + col * 16 + k0);
        aF[L] = pack4(w[0], w[1], w[2], w[3]);
    }
    {
        float4v w = ld16u(W_out + k0);
        if (col != 0) { w[0] = 0.f; w[1] = 0.f; w[2] = 0.f; w[3] = 0.f; }
        aF[NL - 1] = pack4(w[0], w[1], w[2], w[3]);
    }

    const int wave_id = blockIdx.x * WPB + wv;
    int tb = wave_id * T;
    if (tb >= tiles) return;

    // per-lane base pointers; tiles within an iteration via immediate offsets
    const float* xp = x + (size_t)(tb * 16 + col) * S_IN + offk;  // +t*208 floats
    float* op = out + (size_t)tb * 16 + lane;                     // +t*16 floats

    // prefetch first iteration's fragments (16 B per lane per tile)
    float4v w[T];
#pragma unroll
    for (int t = 0; t < T; ++t) w[t] = ld16u(xp + t * 208);

    for (; tb < tiles; tb += STRIDE) {
        // build input-layer B fragments from registers
        short4v bf[T];
#pragma unroll
        for (int t = 0; t < T; ++t) {
            float v0 = g3 ? w[t][3] : w[t][0];
            float v1 = g3 ? 0.f : w[t][1];
            float v2 = g3 ? 0.f : w[t][2];
            float v3 = g3 ? 0.f : w[t][3];
            bf[t] = pack4(v0, v1, v2, v3);
        }

        // prefetch next iteration (in flight across the whole layer chain)
        const int tbn = tb + STRIDE;
        if (tbn < tiles) {
            xp += (size_t)STRIDE * 16 * S_IN;
#pragma unroll
            for (int t = 0; t < T; ++t) w[t] = ld16u(xp + t * 208);
        }

        // 31 layers: bias rides in C operand (one layer ahead), relu + bf16
        // repack feeds the next layer's B fragment in-register.
        float4v cB = biasL[g];
#pragma unroll
        for (int L = 0; L < NL - 1; ++L) {
            const float4v cN = biasL[(L + 1) * 4 + g];
            const short4v aL = aF[L];
            float4v d[T];
#pragma unroll
            for (int t = 0; t < T; ++t)
                d[t] = __builtin_amdgcn_mfma_f32_16x16x16bf16_1k(aL, bf[t], cB, 0, 0, 0);
#pragma unroll
            for (int t = 0; t < T; ++t)
                bf[t] = pack4(fmaxf(d[t][0], 0.f), fmaxf(d[t][1], 0.f),
                              fmaxf(d[t][2], 0.f), fmaxf(d[t][3], 0.f));
            cB = cN;
        }

        // output layer: W_out lives in row 0 only; y[n] = D[0][n]
        const short4v aO = aF[NL - 1];
#pragma unroll
        for (int t = 0; t < T; ++t) {
            float4v d = __builtin_amdgcn_mfma_f32_16x16x16bf16_1k(aO, bf[t], cB, 0, 0, 0);
            if (lane < 16) op[t * 16] = d[0];
        }
        op += (size_t)STRIDE * 16;
    }
}

extern "C" void kernel_launch(void* const* d_in, const int* in_sizes, int n_in,
                              void* d_out, int out_size, void* d_ws, size_t ws_size,
                              hipStream_t stream) {
    const float* x     = (const float*)d_in[0];
    const float* W_in  = (const float*)d_in[1];
    const float* b_in  = (const float*)d_in[2];
    const float* W_h   = (const float*)d_in[3];
    const float* b_h   = (const float*)d_in[4];
    const float* W_out = (const float*)d_in[5];
    const float* b_out = (const float*)d_in[6];
    float* out = (float*)d_out;

    const int tiles = out_size / 16;                       // 131072
    int blocks = (tiles + WPB * T - 1) / (WPB * T);
    if (blocks > NBLOCKS) blocks = NBLOCKS;
    mlp_kernel<<<blocks, TPB, 0, stream>>>(x, W_in, b_in, W_h, b_h, W_out, b_out,
                                           out, tiles);
}